// Round 2
// baseline (589.278 us; speedup 1.0000x reference)
//
#include <hip/hip_runtime.h>

// Soft-circuit FP32 scale-by-2^k, reduced to integer bit ops.
// Row layout (element e <-> bit e of packed word):
//   bit 0      = sign
//   bits 1..8  = exponent, element 1 = MSB (big-endian in element order)
//   bits 9..31 = mantissa, element 9 = MSB
//
// Per row (k word = kw, x word = xw):
//   ek   = int(exponent bits of k)          (8-bit)
//   val  = 0x80 | top7 mantissa bits of k   (8-bit significand)
//   s    = (ek - 127) & 7
//   kabs = val >> (7 - s)
//   kfin = sign_k ? (-kabs) & 0xFF : kabs
//   enew = (ex + kfin) & 0xFF
//   res  = (kw & ~1)==0 ? xw : sign_x | enew(BE) | mant_x
//
// R1: 4x unroll grid-stride to raise MLP (8 independent loads in flight per
// thread) — R0 was latency-bound at 3.0 TB/s with only 2 loads/thread.

#define UNROLL 4

__device__ __forceinline__ unsigned rev8(unsigned v) {
    return __builtin_bitreverse32(v) >> 24;
}

__device__ __forceinline__ unsigned nib4(float4 v) {
    return (unsigned)(v.x != 0.0f)
         | ((unsigned)(v.y != 0.0f) << 1)
         | ((unsigned)(v.z != 0.0f) << 2)
         | ((unsigned)(v.w != 0.0f) << 3);
}

__global__ __launch_bounds__(256) void spike_scale_kernel(
        const float4* __restrict__ x4,
        const float4* __restrict__ k4,
        float4* __restrict__ o4,
        int stride) {   // stride = total threads = nvec / UNROLL
    int tid = blockIdx.x * 256 + threadIdx.x;

    unsigned base = (unsigned)(tid & 7) * 4u;  // this lane's nibble position in the row

    float4 vx[UNROLL], vk[UNROLL];
#pragma unroll
    for (int j = 0; j < UNROLL; ++j) {
        int idx = tid + j * stride;
        vx[j] = x4[idx];
        vk[j] = k4[idx];
    }

    unsigned long long w[UNROLL];
#pragma unroll
    for (int j = 0; j < UNROLL; ++j) {
        w[j] = ((unsigned long long)nib4(vx[j]) << base)
             | ((unsigned long long)nib4(vk[j]) << (32u + base));
    }
#pragma unroll
    for (int j = 0; j < UNROLL; ++j) w[j] |= __shfl_xor(w[j], 1);
#pragma unroll
    for (int j = 0; j < UNROLL; ++j) w[j] |= __shfl_xor(w[j], 2);
#pragma unroll
    for (int j = 0; j < UNROLL; ++j) w[j] |= __shfl_xor(w[j], 4);

#pragma unroll
    for (int j = 0; j < UNROLL; ++j) {
        unsigned xw = (unsigned)w[j];
        unsigned kw = (unsigned)(w[j] >> 32);

        unsigned ek   = rev8((kw >> 1) & 0xFFu);
        unsigned val  = 0x80u | (__builtin_bitreverse32((kw >> 9) & 0x7Fu) >> 25);
        unsigned s    = (ek - 127u) & 7u;
        unsigned kabs = val >> (7u - s);
        unsigned kfin = (kw & 1u) ? ((0u - kabs) & 0xFFu) : kabs;

        unsigned ex   = rev8((xw >> 1) & 0xFFu);
        unsigned enew = (ex + kfin) & 0xFFu;

        unsigned scaled = (xw & 1u) | (rev8(enew) << 1) | (xw & 0xFFFFFE00u);
        unsigned res    = ((kw & ~1u) == 0u) ? xw : scaled;

        float4 out;
        out.x = (float)((res >> (base + 0u)) & 1u);
        out.y = (float)((res >> (base + 1u)) & 1u);
        out.z = (float)((res >> (base + 2u)) & 1u);
        out.w = (float)((res >> (base + 3u)) & 1u);
        o4[tid + j * stride] = out;
    }
}

extern "C" void kernel_launch(void* const* d_in, const int* in_sizes, int n_in,
                              void* d_out, int out_size, void* d_ws, size_t ws_size,
                              hipStream_t stream) {
    const float4* x4 = (const float4*)d_in[0];
    const float4* k4 = (const float4*)d_in[1];
    float4* o4 = (float4*)d_out;

    int n_elems = in_sizes[0];              // N * 32 = 67,108,864
    int nvec    = n_elems / 4;              // 16,777,216 float4 vectors
    int stride  = nvec / UNROLL;            // threads total (multiple of 8)
    int blocks  = stride / 256;             // exact: 16384 blocks

    spike_scale_kernel<<<blocks, 256, 0, stream>>>(x4, k4, o4, stride);
}